// Round 1
// baseline (16846.832 us; speedup 1.0000x reference)
//
#include <hip/hip_runtime.h>

typedef _Float16 f16;
typedef __attribute__((ext_vector_type(4))) _Float16 f16x4;
typedef __attribute__((ext_vector_type(8))) _Float16 f16x8;
typedef __attribute__((ext_vector_type(4))) float f32x4;

#define NT 512

// ---------------------------------------------------------------------------
// GEMM1: xW[t][g][b][j] = sum_k x[b,t,k] * W_ih[g*1024+j, k]   (fp16 out)
// 128x128 tile, BK=32, 4 waves, LDS-staged with inline fp32->fp16 convert.
// LDS rows padded to 40 f16 (80B) to spread banks on ds_read_b128.
// ---------------------------------------------------------------------------
__global__ __launch_bounds__(256) void gemm_xw(
    const float* __restrict__ x,    // [32768, 1024] rows = b*512+t
    const float* __restrict__ Wih,  // [3072, 1024]
    f16* __restrict__ xw)           // [((t*3+g)*64+b)*1024 + j]
{
  const int nblk = blockIdx.x;   // 0..23
  const int mblk = blockIdx.y;   // 0..255
  const int tid  = threadIdx.x;
  const int lane = tid & 63;
  const int wv   = tid >> 6;
  const int wm   = wv >> 1;      // 0..1
  const int wn   = wv & 1;       // 0..1

  __shared__ f16 sA[128 * 40];
  __shared__ f16 sB[128 * 40];

  const int m0 = mblk * 128;
  const int n0 = nblk * 128;

  const int srow = tid >> 3;         // 0..31
  const int scol = (tid & 7) * 4;    // 0..28

  const int lr = lane & 15;
  const int lk = (lane >> 4) * 8;

  f32x4 acc[4][4];
#pragma unroll
  for (int i = 0; i < 4; ++i)
#pragma unroll
    for (int jj = 0; jj < 4; ++jj) acc[i][jj] = (f32x4){0.f, 0.f, 0.f, 0.f};

  for (int kb = 0; kb < 32; ++kb) {
    const int k0 = kb * 32;
#pragma unroll
    for (int rb = 0; rb < 4; ++rb) {
      const int row = srow + rb * 32;
      float4 va = *(const float4*)&x[(size_t)(m0 + row) * 1024 + k0 + scol];
      f16x4 ha; ha[0] = va.x; ha[1] = va.y; ha[2] = va.z; ha[3] = va.w;
      *(f16x4*)&sA[row * 40 + scol] = ha;
      float4 vb = *(const float4*)&Wih[(size_t)(n0 + row) * 1024 + k0 + scol];
      f16x4 hb; hb[0] = vb.x; hb[1] = vb.y; hb[2] = vb.z; hb[3] = vb.w;
      *(f16x4*)&sB[row * 40 + scol] = hb;
    }
    __syncthreads();
    f16x8 af[4], bfr[4];
#pragma unroll
    for (int mi = 0; mi < 4; ++mi)
      af[mi] = *(const f16x8*)&sA[(wm * 64 + mi * 16 + lr) * 40 + lk];
#pragma unroll
    for (int ni = 0; ni < 4; ++ni)
      bfr[ni] = *(const f16x8*)&sB[(wn * 64 + ni * 16 + lr) * 40 + lk];
#pragma unroll
    for (int mi = 0; mi < 4; ++mi)
#pragma unroll
      for (int ni = 0; ni < 4; ++ni)
        acc[mi][ni] = __builtin_amdgcn_mfma_f32_16x16x32_f16(af[mi], bfr[ni], acc[mi][ni], 0, 0, 0);
    __syncthreads();
  }

  // epilogue: D row=(lane>>4)*4+r, col=lane&15 (m89-verified C/D layout)
  const int b  = mblk >> 2;
  const int t0 = (mblk & 3) * 128;
  const int g  = nblk >> 3;
  const int j0 = (nblk & 7) * 128;
#pragma unroll
  for (int mi = 0; mi < 4; ++mi) {
#pragma unroll
    for (int r = 0; r < 4; ++r) {
      const int ri = wm * 64 + mi * 16 + (lane >> 4) * 4 + r;
      const int t  = t0 + ri;
#pragma unroll
      for (int ni = 0; ni < 4; ++ni) {
        const int j = j0 + wn * 64 + ni * 16 + lr;
        xw[(size_t)((t * 3 + g) * 64 + b) * 1024 + j] = (f16)acc[mi][ni][r];
      }
    }
  }
}

// ---------------------------------------------------------------------------
// Recurrence: persistent kernel. Grid (64 unit-chunks, 4 batch-groups),
// 192 threads = 3 waves (wave w = gate w: 0=r, 1=z, 2=n).
// Each wave holds its 16 W_hh rows as 32 fp16 MFMA B-frags in VGPRs.
// Per step: MFMA hW for 16 batches x 16 units x 3 gates; wave2 combines
// gates (hr/hz via LDS) and writes h (fp16 dbuf) + output (fp32).
// Cross-WG sync: per-batch-group 64-flag line, release/acquire, agent scope.
// ---------------------------------------------------------------------------
__device__ __forceinline__ float sigm(float v) { return 1.f / (1.f + __expf(-v)); }
__device__ __forceinline__ float tanh_fast(float v) { return 1.f - 2.f / (1.f + __expf(2.f * v)); }

__global__ __launch_bounds__(192, 1) void recur(
    const f16* __restrict__ xw,      // [((t*3+g)*64+b)*1024 + j]
    const float* __restrict__ mixp,  // [64*512]
    const float* __restrict__ Whh,   // [3072, 1024]
    const float* __restrict__ bih,   // [3072]
    const float* __restrict__ bhh,   // [3072]
    float* __restrict__ out,         // h: [64*512*1024], then o: [64*1024]
    f16* __restrict__ hbuf,          // [2][64*1024]
    int* __restrict__ flags)         // [4][64], memset 0 before launch
{
  const int c = blockIdx.x;          // 0..63 unit chunk
  const int m = blockIdx.y;          // 0..3  batch group
  const int tid = threadIdx.x;
  const int w = tid >> 6;            // gate 0..2
  const int lane = tid & 63;
  const int lr = lane & 15;
  const int lk = (lane >> 4) * 8;
  const int rrow = (lane >> 4) * 4;
  const int m0 = m * 16;
  const int j  = c * 16 + lr;        // hidden unit (column role)
  const int grow = w * 1024 + j;     // W_hh row

  __shared__ float ldsRZ[2][16][16];

  // One-time: convert this wave's W_hh rows to fp16 B-fragments (VGPR-resident).
  f16x8 bf[32];
#pragma unroll
  for (int kc = 0; kc < 32; ++kc) {
    const float* s = &Whh[(size_t)grow * 1024 + kc * 32 + lk];
    float4 v0 = *(const float4*)(s);
    float4 v1 = *(const float4*)(s + 4);
    f16x8 hv;
    hv[0] = v0.x; hv[1] = v0.y; hv[2] = v0.z; hv[3] = v0.w;
    hv[4] = v1.x; hv[5] = v1.y; hv[6] = v1.z; hv[7] = v1.w;
    bf[kc] = hv;
  }
  const float bhw = bhh[grow];
  float bi0 = 0.f, bi1 = 0.f, bi2 = 0.f;
  if (w == 2) { bi0 = bih[j]; bi1 = bih[1024 + j]; bi2 = bih[2048 + j]; }

  float hprev[4] = {0.f, 0.f, 0.f, 0.f};
  int* myflags = &flags[m * 64];

  for (int t = 0; t < NT; ++t) {
    // wave2: issue xW/mix loads early (independent of the flag sync)
    float xr[4], xz[4], xn[4], mt[4];
    if (w == 2) {
#pragma unroll
      for (int r = 0; r < 4; ++r) {
        const int b = m0 + rrow + r;
        xr[r] = (float)xw[(size_t)((t * 3 + 0) * 64 + b) * 1024 + j];
        xz[r] = (float)xw[(size_t)((t * 3 + 1) * 64 + b) * 1024 + j];
        xn[r] = (float)xw[(size_t)((t * 3 + 2) * 64 + b) * 1024 + j];
        mt[r] = mixp[b * 512 + t];
      }
    }
    // wait: all WGs of this batch group finished step t-1
    if (t > 0) {
      int v;
      do {
        v = __hip_atomic_load(&myflags[lane], __ATOMIC_ACQUIRE, __HIP_MEMORY_SCOPE_AGENT);
      } while (v < t);
    }
    // hW = h @ W_hh^T for this wave's gate rows
    f32x4 acc = {0.f, 0.f, 0.f, 0.f};
    if (t > 0) {
      const f16* h = hbuf + (size_t)(t & 1) * (64 * 1024);
      f32x4 a0 = {0,0,0,0}, a1 = {0,0,0,0}, a2 = {0,0,0,0}, a3 = {0,0,0,0};
#pragma unroll
      for (int kc = 0; kc < 32; kc += 4) {
        f16x8 h0 = *(const f16x8*)&h[(m0 + lr) * 1024 + (kc + 0) * 32 + lk];
        f16x8 h1 = *(const f16x8*)&h[(m0 + lr) * 1024 + (kc + 1) * 32 + lk];
        f16x8 h2 = *(const f16x8*)&h[(m0 + lr) * 1024 + (kc + 2) * 32 + lk];
        f16x8 h3 = *(const f16x8*)&h[(m0 + lr) * 1024 + (kc + 3) * 32 + lk];
        a0 = __builtin_amdgcn_mfma_f32_16x16x32_f16(h0, bf[kc + 0], a0, 0, 0, 0);
        a1 = __builtin_amdgcn_mfma_f32_16x16x32_f16(h1, bf[kc + 1], a1, 0, 0, 0);
        a2 = __builtin_amdgcn_mfma_f32_16x16x32_f16(h2, bf[kc + 2], a2, 0, 0, 0);
        a3 = __builtin_amdgcn_mfma_f32_16x16x32_f16(h3, bf[kc + 3], a3, 0, 0, 0);
      }
      acc = (a0 + a1) + (a2 + a3);
    }
    // waves 0,1 publish hr/hz (+b_hh) to LDS
    if (w < 2) {
#pragma unroll
      for (int r = 0; r < 4; ++r) ldsRZ[w][rrow + r][lr] = acc[r] + bhw;
    }
    __syncthreads();
    // wave 2: gate combine, state update, outputs, flag release
    if (w == 2) {
#pragma unroll
      for (int r = 0; r < 4; ++r) {
        const int b = m0 + rrow + r;
        const float hr = ldsRZ[0][rrow + r][lr];
        const float hz = ldsRZ[1][rrow + r][lr];
        const float hn = acc[r] + bhw;
        const float rg = sigm(xr[r] + bi0 + hr);
        const float zg = sigm(xz[r] + bi1 + hz);
        const float ng = tanh_fast(xn[r] + bi2 + rg * hn);
        const float hnew = (1.f - zg) * ng + zg * hprev[r];
        const float mm = mt[r];
        const float hm = mm * hnew + (1.f - mm) * hprev[r];
        hprev[r] = hm;
        out[(size_t)(b * 512 + t) * 1024 + j] = hm;
        hbuf[(size_t)((t + 1) & 1) * (64 * 1024) + b * 1024 + j] = (f16)hm;
        if (t == NT - 1) out[(size_t)64 * 512 * 1024 + (size_t)b * 1024 + j] = hm;
      }
      __threadfence();
      if (lane == 0)
        __hip_atomic_store(&myflags[c], t + 1, __ATOMIC_RELEASE, __HIP_MEMORY_SCOPE_AGENT);
    }
  }
}

// ---------------------------------------------------------------------------
extern "C" void kernel_launch(void* const* d_in, const int* in_sizes, int n_in,
                              void* d_out, int out_size, void* d_ws, size_t ws_size,
                              hipStream_t stream) {
  const float* x    = (const float*)d_in[0];
  const float* mixp = (const float*)d_in[1];
  const float* Wih  = (const float*)d_in[2];
  const float* Whh  = (const float*)d_in[3];
  const float* bih  = (const float*)d_in[4];
  const float* bhh  = (const float*)d_in[5];
  float* out = (float*)d_out;

  const size_t XW_BYTES = (size_t)512 * 3 * 64 * 1024 * sizeof(f16);  // 201326592
  f16* xw    = (f16*)d_ws;
  f16* hbuf  = (f16*)((char*)d_ws + XW_BYTES);
  int* flags = (int*)((char*)d_ws + XW_BYTES + (size_t)2 * 64 * 1024 * sizeof(f16));

  hipMemsetAsync(flags, 0, 4 * 64 * sizeof(int), stream);

  dim3 gg(24, 256);
  gemm_xw<<<gg, 256, 0, stream>>>(x, Wih, xw);

  dim3 gr(64, 4);
  recur<<<gr, 192, 0, stream>>>(xw, mixp, Whh, bih, bhh, out, hbuf, flags);
}

// Round 2
// 9171.529 us; speedup vs baseline: 1.8369x; 1.8369x over previous
//
#include <hip/hip_runtime.h>

typedef _Float16 f16;
typedef __attribute__((ext_vector_type(4))) _Float16 f16x4;
typedef __attribute__((ext_vector_type(8))) _Float16 f16x8;
typedef __attribute__((ext_vector_type(4))) float f32x4;

#define NT 512

// ---------------------------------------------------------------------------
// GEMM1: xW[t][g][b][j] = sum_k x[b,t,k] * W_ih[g*1024+j, k]   (fp16 out)
// 128x128 tile, BK=32, 4 waves, LDS-staged with inline fp32->fp16 convert.
// ---------------------------------------------------------------------------
__global__ __launch_bounds__(256) void gemm_xw(
    const float* __restrict__ x,    // [32768, 1024] rows = b*512+t
    const float* __restrict__ Wih,  // [3072, 1024]
    f16* __restrict__ xw)           // [((t*3+g)*64+b)*1024 + j]
{
  const int nblk = blockIdx.x;   // 0..23
  const int mblk = blockIdx.y;   // 0..255
  const int tid  = threadIdx.x;
  const int lane = tid & 63;
  const int wv   = tid >> 6;
  const int wm   = wv >> 1;      // 0..1
  const int wn   = wv & 1;       // 0..1

  __shared__ f16 sA[128 * 40];
  __shared__ f16 sB[128 * 40];

  const int m0 = mblk * 128;
  const int n0 = nblk * 128;

  const int srow = tid >> 3;         // 0..31
  const int scol = (tid & 7) * 4;    // 0..28

  const int lr = lane & 15;
  const int lk = (lane >> 4) * 8;

  f32x4 acc[4][4];
#pragma unroll
  for (int i = 0; i < 4; ++i)
#pragma unroll
    for (int jj = 0; jj < 4; ++jj) acc[i][jj] = (f32x4){0.f, 0.f, 0.f, 0.f};

  for (int kb = 0; kb < 32; ++kb) {
    const int k0 = kb * 32;
#pragma unroll
    for (int rb = 0; rb < 4; ++rb) {
      const int row = srow + rb * 32;
      float4 va = *(const float4*)&x[(size_t)(m0 + row) * 1024 + k0 + scol];
      f16x4 ha; ha[0] = va.x; ha[1] = va.y; ha[2] = va.z; ha[3] = va.w;
      *(f16x4*)&sA[row * 40 + scol] = ha;
      float4 vb = *(const float4*)&Wih[(size_t)(n0 + row) * 1024 + k0 + scol];
      f16x4 hb; hb[0] = vb.x; hb[1] = vb.y; hb[2] = vb.z; hb[3] = vb.w;
      *(f16x4*)&sB[row * 40 + scol] = hb;
    }
    __syncthreads();
    f16x8 af[4], bfr[4];
#pragma unroll
    for (int mi = 0; mi < 4; ++mi)
      af[mi] = *(const f16x8*)&sA[(wm * 64 + mi * 16 + lr) * 40 + lk];
#pragma unroll
    for (int ni = 0; ni < 4; ++ni)
      bfr[ni] = *(const f16x8*)&sB[(wn * 64 + ni * 16 + lr) * 40 + lk];
#pragma unroll
    for (int mi = 0; mi < 4; ++mi)
#pragma unroll
      for (int ni = 0; ni < 4; ++ni)
        acc[mi][ni] = __builtin_amdgcn_mfma_f32_16x16x32_f16(af[mi], bfr[ni], acc[mi][ni], 0, 0, 0);
    __syncthreads();
  }

  const int b  = mblk >> 2;
  const int t0 = (mblk & 3) * 128;
  const int g  = nblk >> 3;
  const int j0 = (nblk & 7) * 128;
#pragma unroll
  for (int mi = 0; mi < 4; ++mi) {
#pragma unroll
    for (int r = 0; r < 4; ++r) {
      const int ri = wm * 64 + mi * 16 + (lane >> 4) * 4 + r;
      const int t  = t0 + ri;
#pragma unroll
      for (int ni = 0; ni < 4; ++ni) {
        const int j = j0 + wn * 64 + ni * 16 + lr;
        xw[(size_t)((t * 3 + g) * 64 + b) * 1024 + j] = (f16)acc[mi][ni][r];
      }
    }
  }
}

// ---------------------------------------------------------------------------
// Recurrence: persistent kernel. Grid (64 unit-chunks, 4 batch-groups),
// 192 threads = 3 waves (wave w = gate w: 0=r, 1=z, 2=n).
// Protocol per step:
//   spin RELAXED on group's 64 flags -> ONE acquire fence -> cooperative
//   h(global)->LDS stage (XOR-swizzled) -> MFMA from LDS -> waves0/1 publish
//   hr/hz -> wave2 combines, writes h + out, ONE release fence + flag store.
// ---------------------------------------------------------------------------
__device__ __forceinline__ float sigm(float v) { return 1.f / (1.f + __expf(-v)); }
__device__ __forceinline__ float tanh_fast(float v) { return 1.f - 2.f / (1.f + __expf(2.f * v)); }

__global__ __launch_bounds__(192, 1) void recur(
    const f16* __restrict__ xw,      // [((t*3+g)*64+b)*1024 + j]
    const float* __restrict__ mixp,  // [64*512]
    const float* __restrict__ Whh,   // [3072, 1024]
    const float* __restrict__ bih,   // [3072]
    const float* __restrict__ bhh,   // [3072]
    float* __restrict__ out,         // h: [64*512*1024], then o: [64*1024]
    f16* __restrict__ hbuf,          // [2][64*1024]
    int* __restrict__ flags)         // [4][64], memset 0 before launch
{
  const int c = blockIdx.x;          // 0..63 unit chunk
  const int m = blockIdx.y;          // 0..3  batch group
  const int tid = threadIdx.x;
  const int w = tid >> 6;            // gate 0..2
  const int lane = tid & 63;
  const int lr = lane & 15;
  const int lk = (lane >> 4) * 8;
  const int rrow = (lane >> 4) * 4;
  const int m0 = m * 16;
  const int j  = c * 16 + lr;        // hidden unit (column role)
  const int grow = w * 1024 + j;     // W_hh row

  __shared__ float smix[16][512];    // 32 KB: mix for this batch group
  __shared__ f16 hstage[16 * 1024];  // 32 KB: h tile, chunk-XOR-swizzled
  __shared__ float ldsRZ[2][16][16];

  // preload mix (16 rows x 128 float4)
  for (int i = tid; i < 2048; i += 192) {
    const int row = i >> 7;
    const int col = (i & 127) * 4;
    *(float4*)&smix[row][col] = *(const float4*)&mixp[(m0 + row) * 512 + col];
  }

  // One-time: this wave's W_hh rows as fp16 B-fragments (VGPR-resident).
  f16x8 bf[32];
#pragma unroll
  for (int kc = 0; kc < 32; ++kc) {
    const float* s = &Whh[(size_t)grow * 1024 + kc * 32 + lk];
    float4 v0 = *(const float4*)(s);
    float4 v1 = *(const float4*)(s + 4);
    f16x8 hv;
    hv[0] = v0.x; hv[1] = v0.y; hv[2] = v0.z; hv[3] = v0.w;
    hv[4] = v1.x; hv[5] = v1.y; hv[6] = v1.z; hv[7] = v1.w;
    bf[kc] = hv;
  }
  const float bhw = bhh[grow];
  float bi0 = 0.f, bi1 = 0.f, bi2 = 0.f;
  if (w == 2) { bi0 = bih[j]; bi1 = bih[1024 + j]; bi2 = bih[2048 + j]; }

  float hprev[4] = {0.f, 0.f, 0.f, 0.f};
  int* myflags = &flags[m * 64];

  __syncthreads();  // smix ready

  for (int t = 0; t < NT; ++t) {
    // wave2: issue xW loads early (nontemporal: each element read once)
    float xr[4], xz[4], xn[4], mt[4];
    if (w == 2) {
#pragma unroll
      for (int r = 0; r < 4; ++r) {
        const int b = m0 + rrow + r;
        xr[r] = (float)__builtin_nontemporal_load(&xw[(size_t)((t * 3 + 0) * 64 + b) * 1024 + j]);
        xz[r] = (float)__builtin_nontemporal_load(&xw[(size_t)((t * 3 + 1) * 64 + b) * 1024 + j]);
        xn[r] = (float)__builtin_nontemporal_load(&xw[(size_t)((t * 3 + 2) * 64 + b) * 1024 + j]);
        mt[r] = smix[rrow + r][t];
      }
    }
    if (t > 0) {
      // spin RELAXED (no per-poll invalidate), then one acquire fence
      while (__hip_atomic_load(&myflags[lane], __ATOMIC_RELAXED,
                               __HIP_MEMORY_SCOPE_AGENT) < t) {}
      __builtin_amdgcn_fence(__ATOMIC_ACQUIRE, "agent");
      // cooperative h -> LDS, chunk (16B) XOR-swizzled by row&7
      const f16* h = hbuf + (size_t)(t & 1) * (64 * 1024);
      for (int i = tid; i < 2048; i += 192) {
        const int row = i >> 7;
        const int chunk = (i & 127) ^ (row & 7);
        *(f16x8*)&hstage[row * 1024 + chunk * 8] =
            *(const f16x8*)&h[(size_t)(m0 + row) * 1024 + (i & 127) * 8];
      }
    }
    __syncthreads();  // hstage ready
    f32x4 acc = {0.f, 0.f, 0.f, 0.f};
    if (t > 0) {
      f32x4 a0 = {0,0,0,0}, a1 = {0,0,0,0}, a2 = {0,0,0,0}, a3 = {0,0,0,0};
#pragma unroll
      for (int kc = 0; kc < 32; kc += 4) {
        // A-frag row = batch (lr), chunk index = kc*4 + lk/8, swizzled by lr&7
        f16x8 h0 = *(const f16x8*)&hstage[lr * 1024 + ((((kc + 0) * 4 + (lk >> 3)) ^ (lr & 7)) * 8)];
        f16x8 h1 = *(const f16x8*)&hstage[lr * 1024 + ((((kc + 1) * 4 + (lk >> 3)) ^ (lr & 7)) * 8)];
        f16x8 h2 = *(const f16x8*)&hstage[lr * 1024 + ((((kc + 2) * 4 + (lk >> 3)) ^ (lr & 7)) * 8)];
        f16x8 h3 = *(const f16x8*)&hstage[lr * 1024 + ((((kc + 3) * 4 + (lk >> 3)) ^ (lr & 7)) * 8)];
        a0 = __builtin_amdgcn_mfma_f32_16x16x32_f16(h0, bf[kc + 0], a0, 0, 0, 0);
        a1 = __builtin_amdgcn_mfma_f32_16x16x32_f16(h1, bf[kc + 1], a1, 0, 0, 0);
        a2 = __builtin_amdgcn_mfma_f32_16x16x32_f16(h2, bf[kc + 2], a2, 0, 0, 0);
        a3 = __builtin_amdgcn_mfma_f32_16x16x32_f16(h3, bf[kc + 3], a3, 0, 0, 0);
      }
      acc = (a0 + a1) + (a2 + a3);
    }
    // waves 0,1 publish hr/hz (+b_hh) to LDS
    if (w < 2) {
#pragma unroll
      for (int r = 0; r < 4; ++r) ldsRZ[w][rrow + r][lr] = acc[r] + bhw;
    }
    __syncthreads();
    // wave 2: gate combine, state update, outputs, flag release
    if (w == 2) {
#pragma unroll
      for (int r = 0; r < 4; ++r) {
        const int b = m0 + rrow + r;
        const float hr = ldsRZ[0][rrow + r][lr];
        const float hz = ldsRZ[1][rrow + r][lr];
        const float hn = acc[r] + bhw;
        const float rg = sigm(xr[r] + bi0 + hr);
        const float zg = sigm(xz[r] + bi1 + hz);
        const float ng = tanh_fast(xn[r] + bi2 + rg * hn);
        const float hnew = (1.f - zg) * ng + zg * hprev[r];
        const float mm = mt[r];
        const float hm = mm * hnew + (1.f - mm) * hprev[r];
        hprev[r] = hm;
        __builtin_nontemporal_store(hm, &out[(size_t)(b * 512 + t) * 1024 + j]);
        hbuf[(size_t)((t + 1) & 1) * (64 * 1024) + (size_t)b * 1024 + j] = (f16)hm;
        if (t == NT - 1)
          __builtin_nontemporal_store(hm, &out[(size_t)64 * 512 * 1024 + (size_t)b * 1024 + j]);
      }
      __builtin_amdgcn_fence(__ATOMIC_RELEASE, "agent");
      if (lane == 0)
        __hip_atomic_store(&myflags[c], t + 1, __ATOMIC_RELAXED, __HIP_MEMORY_SCOPE_AGENT);
    }
  }
}

// ---------------------------------------------------------------------------
extern "C" void kernel_launch(void* const* d_in, const int* in_sizes, int n_in,
                              void* d_out, int out_size, void* d_ws, size_t ws_size,
                              hipStream_t stream) {
  const float* x    = (const float*)d_in[0];
  const float* mixp = (const float*)d_in[1];
  const float* Wih  = (const float*)d_in[2];
  const float* Whh  = (const float*)d_in[3];
  const float* bih  = (const float*)d_in[4];
  const float* bhh  = (const float*)d_in[5];
  float* out = (float*)d_out;

  const size_t XW_BYTES = (size_t)512 * 3 * 64 * 1024 * sizeof(f16);  // 201326592
  f16* xw    = (f16*)d_ws;
  f16* hbuf  = (f16*)((char*)d_ws + XW_BYTES);
  int* flags = (int*)((char*)d_ws + XW_BYTES + (size_t)2 * 64 * 1024 * sizeof(f16));

  hipMemsetAsync(flags, 0, 4 * 64 * sizeof(int), stream);

  dim3 gg(24, 256);
  gemm_xw<<<gg, 256, 0, stream>>>(x, Wih, xw);

  dim3 gr(64, 4);
  recur<<<gr, 192, 0, stream>>>(xw, mixp, Whh, bih, bhh, out, hbuf, flags);
}

// Round 3
// 3255.116 us; speedup vs baseline: 5.1755x; 2.8176x over previous
//
#include <hip/hip_runtime.h>

typedef _Float16 f16;
typedef __attribute__((ext_vector_type(4))) _Float16 f16x4;
typedef __attribute__((ext_vector_type(8))) _Float16 f16x8;
typedef __attribute__((ext_vector_type(4))) float f32x4;

#define NT 512

// ---------------------------------------------------------------------------
// GEMM1: xW[t][g][b][j] = sum_k x[b,t,k] * W_ih[g*1024+j, k]   (fp16 out)
// ---------------------------------------------------------------------------
__global__ __launch_bounds__(256) void gemm_xw(
    const float* __restrict__ x,    // [32768, 1024] rows = b*512+t
    const float* __restrict__ Wih,  // [3072, 1024]
    f16* __restrict__ xw)           // [((t*3+g)*64+b)*1024 + j]
{
  const int nblk = blockIdx.x;   // 0..23
  const int mblk = blockIdx.y;   // 0..255
  const int tid  = threadIdx.x;
  const int lane = tid & 63;
  const int wv   = tid >> 6;
  const int wm   = wv >> 1;      // 0..1
  const int wn   = wv & 1;       // 0..1

  __shared__ f16 sA[128 * 40];
  __shared__ f16 sB[128 * 40];

  const int m0 = mblk * 128;
  const int n0 = nblk * 128;

  const int srow = tid >> 3;         // 0..31
  const int scol = (tid & 7) * 4;    // 0..28

  const int lr = lane & 15;
  const int lk = (lane >> 4) * 8;

  f32x4 acc[4][4];
#pragma unroll
  for (int i = 0; i < 4; ++i)
#pragma unroll
    for (int jj = 0; jj < 4; ++jj) acc[i][jj] = (f32x4){0.f, 0.f, 0.f, 0.f};

  for (int kb = 0; kb < 32; ++kb) {
    const int k0 = kb * 32;
#pragma unroll
    for (int rb = 0; rb < 4; ++rb) {
      const int row = srow + rb * 32;
      float4 va = *(const float4*)&x[(size_t)(m0 + row) * 1024 + k0 + scol];
      f16x4 ha; ha[0] = va.x; ha[1] = va.y; ha[2] = va.z; ha[3] = va.w;
      *(f16x4*)&sA[row * 40 + scol] = ha;
      float4 vb = *(const float4*)&Wih[(size_t)(n0 + row) * 1024 + k0 + scol];
      f16x4 hb; hb[0] = vb.x; hb[1] = vb.y; hb[2] = vb.z; hb[3] = vb.w;
      *(f16x4*)&sB[row * 40 + scol] = hb;
    }
    __syncthreads();
    f16x8 af[4], bfr[4];
#pragma unroll
    for (int mi = 0; mi < 4; ++mi)
      af[mi] = *(const f16x8*)&sA[(wm * 64 + mi * 16 + lr) * 40 + lk];
#pragma unroll
    for (int ni = 0; ni < 4; ++ni)
      bfr[ni] = *(const f16x8*)&sB[(wn * 64 + ni * 16 + lr) * 40 + lk];
#pragma unroll
    for (int mi = 0; mi < 4; ++mi)
#pragma unroll
      for (int ni = 0; ni < 4; ++ni)
        acc[mi][ni] = __builtin_amdgcn_mfma_f32_16x16x32_f16(af[mi], bfr[ni], acc[mi][ni], 0, 0, 0);
    __syncthreads();
  }

  const int b  = mblk >> 2;
  const int t0 = (mblk & 3) * 128;
  const int g  = nblk >> 3;
  const int j0 = (nblk & 7) * 128;
#pragma unroll
  for (int mi = 0; mi < 4; ++mi) {
#pragma unroll
    for (int r = 0; r < 4; ++r) {
      const int ri = wm * 64 + mi * 16 + (lane >> 4) * 4 + r;
      const int t  = t0 + ri;
#pragma unroll
      for (int ni = 0; ni < 4; ++ni) {
        const int j = j0 + wn * 64 + ni * 16 + lr;
        xw[(size_t)((t * 3 + g) * 64 + b) * 1024 + j] = (f16)acc[mi][ni][r];
      }
    }
  }
}

// ---------------------------------------------------------------------------
// Recurrence: persistent kernel, 64 unit-chunks x 4 batch-groups, 3 waves/WG.
// Cross-WG protocol is FENCE-FREE: all shared state (hbuf, flags) moves via
// sc0 sc1 (LLC-direct, coherence-point) loads/stores; ordering via one
// s_waitcnt vmcnt(0) between data stores and flag store. No buffer_inv /
// buffer_wbl2 per step.
// ---------------------------------------------------------------------------
__device__ __forceinline__ float sigm(float v) { return 1.f / (1.f + __expf(-v)); }
__device__ __forceinline__ float tanh_fast(float v) { return 1.f - 2.f / (1.f + __expf(2.f * v)); }

__global__ __launch_bounds__(192, 1) void recur(
    const f16* __restrict__ xw,      // [((t*3+g)*64+b)*1024 + j]
    const float* __restrict__ mixp,  // [64*512]
    const float* __restrict__ Whh,   // [3072, 1024]
    const float* __restrict__ bih,   // [3072]
    const float* __restrict__ bhh,   // [3072]
    float* __restrict__ out,         // h: [64*512*1024], then o: [64*1024]
    f16* __restrict__ hbuf,          // [2][64*1024]
    int* __restrict__ flags)         // [4][64], memset 0 before launch
{
  const int c = blockIdx.x;          // 0..63 unit chunk
  const int m = blockIdx.y;          // 0..3  batch group
  const int tid = threadIdx.x;
  const int w = tid >> 6;            // gate 0..2
  const int lane = tid & 63;
  const int lr = lane & 15;
  const int lk = (lane >> 4) * 8;
  const int rrow = (lane >> 4) * 4;
  const int m0 = m * 16;
  const int j  = c * 16 + lr;        // hidden unit (column role)
  const int grow = w * 1024 + j;     // W_hh row

  __shared__ float smix[16][512];    // 32 KB
  __shared__ f16 hstage[16 * 1024];  // 32 KB, chunk-XOR-swizzled
  __shared__ float ldsRZ[2][16][16];

  for (int i = tid; i < 2048; i += 192) {
    const int row = i >> 7;
    const int col = (i & 127) * 4;
    *(float4*)&smix[row][col] = *(const float4*)&mixp[(m0 + row) * 512 + col];
  }

  // W_hh rows as fp16 B-fragments, VGPR-resident.
  f16x8 bf[32];
#pragma unroll
  for (int kc = 0; kc < 32; ++kc) {
    const float* s = &Whh[(size_t)grow * 1024 + kc * 32 + lk];
    float4 v0 = *(const float4*)(s);
    float4 v1 = *(const float4*)(s + 4);
    f16x8 hv;
    hv[0] = v0.x; hv[1] = v0.y; hv[2] = v0.z; hv[3] = v0.w;
    hv[4] = v1.x; hv[5] = v1.y; hv[6] = v1.z; hv[7] = v1.w;
    bf[kc] = hv;
  }
  const float bhw = bhh[grow];
  float bi0 = 0.f, bi1 = 0.f, bi2 = 0.f;
  if (w == 2) { bi0 = bih[j]; bi1 = bih[1024 + j]; bi2 = bih[2048 + j]; }

  float hprev[4] = {0.f, 0.f, 0.f, 0.f};
  int* myflags = &flags[m * 64];

  __syncthreads();  // smix ready

  for (int t = 0; t < NT; ++t) {
    // wave2: xW loads early (consumed after spin; covered by spin latency)
    float xr[4], xz[4], xn[4], mt[4];
    if (w == 2) {
#pragma unroll
      for (int r = 0; r < 4; ++r) {
        const int b = m0 + rrow + r;
        xr[r] = (float)__builtin_nontemporal_load(&xw[(size_t)((t * 3 + 0) * 64 + b) * 1024 + j]);
        xz[r] = (float)__builtin_nontemporal_load(&xw[(size_t)((t * 3 + 1) * 64 + b) * 1024 + j]);
        xn[r] = (float)__builtin_nontemporal_load(&xw[(size_t)((t * 3 + 2) * 64 + b) * 1024 + j]);
        mt[r] = smix[rrow + r][t];
      }
    }
    if (t > 0) {
      // spin: relaxed agent loads (sc1 dword, no cache maintenance)
      while (__hip_atomic_load(&myflags[lane], __ATOMIC_RELAXED,
                               __HIP_MEMORY_SCOPE_AGENT) < t) {}
      // h -> LDS: LLC-direct loads (sc0 sc1), batched, one waitcnt, then
      // identity-asm barrier per value so stores can't sink above waitcnt.
      const f16* base = hbuf + (size_t)(t & 1) * (64 * 1024) + (size_t)m0 * 1024;
      f16x8 v[11];
#pragma unroll
      for (int jj = 0; jj < 10; ++jj) {
        const f16* p = base + (tid + 192 * jj) * 8;
        asm volatile("global_load_dwordx4 %0, %1, off sc0 sc1"
                     : "=v"(v[jj]) : "v"(p));
      }
      if (tid < 128) {  // waves 0,1 only (wave-uniform)
        const f16* p = base + (tid + 1920) * 8;
        asm volatile("global_load_dwordx4 %0, %1, off sc0 sc1"
                     : "=v"(v[10]) : "v"(p));
      }
      asm volatile("s_waitcnt vmcnt(0)" ::: "memory");
#pragma unroll
      for (int jj = 0; jj < 10; ++jj) {
        asm volatile("" : "+v"(v[jj]));
        const int i = tid + 192 * jj;
        const int row = i >> 7;
        const int ch = (i & 127) ^ (row & 7);
        *(f16x8*)&hstage[row * 1024 + ch * 8] = v[jj];
      }
      if (tid < 128) {
        asm volatile("" : "+v"(v[10]));
        const int i = tid + 1920;
        const int row = i >> 7;
        const int ch = (i & 127) ^ (row & 7);
        *(f16x8*)&hstage[row * 1024 + ch * 8] = v[10];
      }
    }
    __syncthreads();  // hstage ready
    f32x4 acc = {0.f, 0.f, 0.f, 0.f};
    if (t > 0) {
      f32x4 a0 = {0,0,0,0}, a1 = {0,0,0,0}, a2 = {0,0,0,0}, a3 = {0,0,0,0};
#pragma unroll
      for (int kc = 0; kc < 32; kc += 4) {
        f16x8 h0 = *(const f16x8*)&hstage[lr * 1024 + ((((kc + 0) * 4 + (lk >> 3)) ^ (lr & 7)) * 8)];
        f16x8 h1 = *(const f16x8*)&hstage[lr * 1024 + ((((kc + 1) * 4 + (lk >> 3)) ^ (lr & 7)) * 8)];
        f16x8 h2 = *(const f16x8*)&hstage[lr * 1024 + ((((kc + 2) * 4 + (lk >> 3)) ^ (lr & 7)) * 8)];
        f16x8 h3 = *(const f16x8*)&hstage[lr * 1024 + ((((kc + 3) * 4 + (lk >> 3)) ^ (lr & 7)) * 8)];
        a0 = __builtin_amdgcn_mfma_f32_16x16x32_f16(h0, bf[kc + 0], a0, 0, 0, 0);
        a1 = __builtin_amdgcn_mfma_f32_16x16x32_f16(h1, bf[kc + 1], a1, 0, 0, 0);
        a2 = __builtin_amdgcn_mfma_f32_16x16x32_f16(h2, bf[kc + 2], a2, 0, 0, 0);
        a3 = __builtin_amdgcn_mfma_f32_16x16x32_f16(h3, bf[kc + 3], a3, 0, 0, 0);
      }
      acc = (a0 + a1) + (a2 + a3);
    }
    if (w < 2) {
#pragma unroll
      for (int r = 0; r < 4; ++r) ldsRZ[w][rrow + r][lr] = acc[r] + bhw;
    }
    __syncthreads();
    if (w == 2) {
      float hmv[4];
#pragma unroll
      for (int r = 0; r < 4; ++r) {
        const float hr = ldsRZ[0][rrow + r][lr];
        const float hz = ldsRZ[1][rrow + r][lr];
        const float hn = acc[r] + bhw;
        const float rg = sigm(xr[r] + bi0 + hr);
        const float zg = sigm(xz[r] + bi1 + hz);
        const float ng = tanh_fast(xn[r] + bi2 + rg * hn);
        const float hnew = (1.f - zg) * ng + zg * hprev[r];
        const float mm = mt[r];
        const float hm = mm * hnew + (1.f - mm) * hprev[r];
        hprev[r] = hm;
        hmv[r] = hm;
      }
      // h stores: LLC-direct (sc0 sc1) -> waitcnt -> flag (shortest path)
      f16* hb = hbuf + (size_t)((t + 1) & 1) * (64 * 1024);
#pragma unroll
      for (int r = 0; r < 4; ++r) {
        f16* p = hb + (size_t)(m0 + rrow + r) * 1024 + j;
        unsigned short u = __builtin_bit_cast(unsigned short, (f16)hmv[r]);
        asm volatile("global_store_short %0, %1, off sc0 sc1"
                     :: "v"(p), "v"(u) : "memory");
      }
      asm volatile("s_waitcnt vmcnt(0)" ::: "memory");
      if (lane == 0)
        __hip_atomic_store(&myflags[c], t + 1, __ATOMIC_RELAXED, __HIP_MEMORY_SCOPE_AGENT);
      // bulk outputs after the release (off the critical path)
#pragma unroll
      for (int r = 0; r < 4; ++r) {
        const int b = m0 + rrow + r;
        __builtin_nontemporal_store(hmv[r], &out[(size_t)(b * 512 + t) * 1024 + j]);
        if (t == NT - 1)
          __builtin_nontemporal_store(hmv[r], &out[(size_t)64 * 512 * 1024 + (size_t)b * 1024 + j]);
      }
    }
  }
}

// ---------------------------------------------------------------------------
extern "C" void kernel_launch(void* const* d_in, const int* in_sizes, int n_in,
                              void* d_out, int out_size, void* d_ws, size_t ws_size,
                              hipStream_t stream) {
  const float* x    = (const float*)d_in[0];
  const float* mixp = (const float*)d_in[1];
  const float* Wih  = (const float*)d_in[2];
  const float* Whh  = (const float*)d_in[3];
  const float* bih  = (const float*)d_in[4];
  const float* bhh  = (const float*)d_in[5];
  float* out = (float*)d_out;

  const size_t XW_BYTES = (size_t)512 * 3 * 64 * 1024 * sizeof(f16);  // 201326592
  f16* xw    = (f16*)d_ws;
  f16* hbuf  = (f16*)((char*)d_ws + XW_BYTES);
  int* flags = (int*)((char*)d_ws + XW_BYTES + (size_t)2 * 64 * 1024 * sizeof(f16));

  hipMemsetAsync(flags, 0, 4 * 64 * sizeof(int), stream);

  dim3 gg(24, 256);
  gemm_xw<<<gg, 256, 0, stream>>>(x, Wih, xw);

  dim3 gr(64, 4);
  recur<<<gr, 192, 0, stream>>>(xw, mixp, Whh, bih, bhh, out, hbuf, flags);
}

// Round 4
// 3231.799 us; speedup vs baseline: 5.2128x; 1.0072x over previous
//
#include <hip/hip_runtime.h>

typedef _Float16 f16;
typedef __attribute__((ext_vector_type(4))) _Float16 f16x4;
typedef __attribute__((ext_vector_type(8))) _Float16 f16x8;
typedef __attribute__((ext_vector_type(4))) float f32x4;

#define NT 512

// ---------------------------------------------------------------------------
// GEMM1: xW[t][g][b][j] = sum_k x[b,t,k] * W_ih[g*1024+j, k]   (fp16 out)
// ---------------------------------------------------------------------------
__global__ __launch_bounds__(256) void gemm_xw(
    const float* __restrict__ x,    // [32768, 1024] rows = b*512+t
    const float* __restrict__ Wih,  // [3072, 1024]
    f16* __restrict__ xw)           // [((t*3+g)*64+b)*1024 + j]
{
  const int nblk = blockIdx.x;   // 0..23
  const int mblk = blockIdx.y;   // 0..255
  const int tid  = threadIdx.x;
  const int lane = tid & 63;
  const int wv   = tid >> 6;
  const int wm   = wv >> 1;      // 0..1
  const int wn   = wv & 1;       // 0..1

  __shared__ f16 sA[128 * 40];
  __shared__ f16 sB[128 * 40];

  const int m0 = mblk * 128;
  const int n0 = nblk * 128;

  const int srow = tid >> 3;         // 0..31
  const int scol = (tid & 7) * 4;    // 0..28

  const int lr = lane & 15;
  const int lk = (lane >> 4) * 8;

  f32x4 acc[4][4];
#pragma unroll
  for (int i = 0; i < 4; ++i)
#pragma unroll
    for (int jj = 0; jj < 4; ++jj) acc[i][jj] = (f32x4){0.f, 0.f, 0.f, 0.f};

  for (int kb = 0; kb < 32; ++kb) {
    const int k0 = kb * 32;
#pragma unroll
    for (int rb = 0; rb < 4; ++rb) {
      const int row = srow + rb * 32;
      float4 va = *(const float4*)&x[(size_t)(m0 + row) * 1024 + k0 + scol];
      f16x4 ha; ha[0] = va.x; ha[1] = va.y; ha[2] = va.z; ha[3] = va.w;
      *(f16x4*)&sA[row * 40 + scol] = ha;
      float4 vb = *(const float4*)&Wih[(size_t)(n0 + row) * 1024 + k0 + scol];
      f16x4 hb; hb[0] = vb.x; hb[1] = vb.y; hb[2] = vb.z; hb[3] = vb.w;
      *(f16x4*)&sB[row * 40 + scol] = hb;
    }
    __syncthreads();
    f16x8 af[4], bfr[4];
#pragma unroll
    for (int mi = 0; mi < 4; ++mi)
      af[mi] = *(const f16x8*)&sA[(wm * 64 + mi * 16 + lr) * 40 + lk];
#pragma unroll
    for (int ni = 0; ni < 4; ++ni)
      bfr[ni] = *(const f16x8*)&sB[(wn * 64 + ni * 16 + lr) * 40 + lk];
#pragma unroll
    for (int mi = 0; mi < 4; ++mi)
#pragma unroll
      for (int ni = 0; ni < 4; ++ni)
        acc[mi][ni] = __builtin_amdgcn_mfma_f32_16x16x32_f16(af[mi], bfr[ni], acc[mi][ni], 0, 0, 0);
    __syncthreads();
  }

  const int b  = mblk >> 2;
  const int t0 = (mblk & 3) * 128;
  const int g  = nblk >> 3;
  const int j0 = (nblk & 7) * 128;
#pragma unroll
  for (int mi = 0; mi < 4; ++mi) {
#pragma unroll
    for (int r = 0; r < 4; ++r) {
      const int ri = wm * 64 + mi * 16 + (lane >> 4) * 4 + r;
      const int t  = t0 + ri;
#pragma unroll
      for (int ni = 0; ni < 4; ++ni) {
        const int j = j0 + wn * 64 + ni * 16 + lr;
        xw[(size_t)((t * 3 + g) * 64 + b) * 1024 + j] = (f16)acc[mi][ni][r];
      }
    }
  }
}

// ---------------------------------------------------------------------------
// Recurrence: persistent kernel, 64 unit-chunks x 4 batch-groups, 3 waves/WG.
// Role split:
//   waves 0/1 (consumers): spin on their HALF of the flag line (writers
//     0..31 / 32..63), then stage their half of h -> LDS (sc0sc1 loads,
//     source-XOR-swizzled). Never touch stores.
//   wave 2 (producer): never polls. MFMA n-gate, combine, h-store sc0sc1,
//     vmcnt(0), flag store; out-stores + next-step xw prefetch AFTER flag.
// 2 barriers/step. All cross-WG state via LLC-direct (sc0 sc1), fence-free.
// ---------------------------------------------------------------------------
__device__ __forceinline__ float sigm(float v) { return 1.f / (1.f + __expf(-v)); }
__device__ __forceinline__ float tanh_fast(float v) { return 1.f - 2.f / (1.f + __expf(2.f * v)); }

__global__ __launch_bounds__(192, 1) void recur(
    const f16* __restrict__ xw,      // [((t*3+g)*64+b)*1024 + j]
    const float* __restrict__ mixp,  // [64*512]
    const float* __restrict__ Whh,   // [3072, 1024]
    const float* __restrict__ bih,   // [3072]
    const float* __restrict__ bhh,   // [3072]
    float* __restrict__ out,         // h: [64*512*1024], then o: [64*1024]
    f16* __restrict__ hbuf,          // [2][64*1024]
    int* __restrict__ flags)         // [4][64], memset 0 before launch
{
  const int c = blockIdx.x;          // 0..63 unit chunk
  const int m = blockIdx.y;          // 0..3  batch group
  const int tid = threadIdx.x;
  const int w = tid >> 6;            // 0,1 consumers; 2 producer
  const int lane = tid & 63;
  const int lr = lane & 15;
  const int lk = (lane >> 4) * 8;
  const int rrow = (lane >> 4) * 4;
  const int m0 = m * 16;
  const int j  = c * 16 + lr;        // hidden unit (column role)
  const int grow = w * 1024 + j;     // W_hh row

  __shared__ float smix[16][512];    // 32 KB
  __shared__ f16 hstage[16 * 1024];  // 32 KB, chunk-XOR-swizzled
  __shared__ float ldsRZ[2][16][16];

  for (int i = tid; i < 2048; i += 192) {
    const int row = i >> 7;
    const int col = (i & 127) * 4;
    *(float4*)&smix[row][col] = *(const float4*)&mixp[(m0 + row) * 512 + col];
  }

  // W_hh rows as fp16 B-fragments, VGPR-resident.
  f16x8 bf[32];
#pragma unroll
  for (int kc = 0; kc < 32; ++kc) {
    const float* s = &Whh[(size_t)grow * 1024 + kc * 32 + lk];
    float4 v0 = *(const float4*)(s);
    float4 v1 = *(const float4*)(s + 4);
    f16x8 hv;
    hv[0] = v0.x; hv[1] = v0.y; hv[2] = v0.z; hv[3] = v0.w;
    hv[4] = v1.x; hv[5] = v1.y; hv[6] = v1.z; hv[7] = v1.w;
    bf[kc] = hv;
  }
  const float bhw = bhh[grow];
  float bi0 = 0.f, bi1 = 0.f, bi2 = 0.f;
  if (w == 2) { bi0 = bih[j]; bi1 = bih[1024 + j]; bi2 = bih[2048 + j]; }

  float hprev[4] = {0.f, 0.f, 0.f, 0.f};
  int* myflags = &flags[m * 64];

  __syncthreads();  // smix ready

  // producer prologue: xW(0) + mix(0)
  float xr[4], xz[4], xn[4], mt[4];
  if (w == 2) {
#pragma unroll
    for (int r = 0; r < 4; ++r) {
      const int b = m0 + rrow + r;
      xr[r] = (float)__builtin_nontemporal_load(&xw[(size_t)(0 * 64 + b) * 1024 + j]);
      xz[r] = (float)__builtin_nontemporal_load(&xw[(size_t)(1 * 64 + b) * 1024 + j]);
      xn[r] = (float)__builtin_nontemporal_load(&xw[(size_t)(2 * 64 + b) * 1024 + j]);
      mt[r] = smix[rrow + r][0];
    }
  }

  for (int t = 0; t < NT; ++t) {
    if (t > 0 && w < 2) {
      // consumers: spin on OUR half of the flags (writers w*32 .. w*32+31)
      while (__hip_atomic_load(&myflags[w * 32 + (lane & 31)], __ATOMIC_RELAXED,
                               __HIP_MEMORY_SCOPE_AGENT) < t) {}
      // stage our half: rows 0..15, chunks [w*64, w*64+64). Source address
      // XOR-swizzled so LDS[row][q] = h[row][q ^ (row&7)].
      const f16* hsrc = hbuf + (size_t)(t & 1) * (64 * 1024) + (size_t)m0 * 1024;
      f16x8 v[16];
#pragma unroll
      for (int jj = 0; jj < 16; ++jj) {
        const f16* p = hsrc + (size_t)jj * 1024 + (w * 64 + (lane ^ (jj & 7))) * 8;
        asm volatile("global_load_dwordx4 %0, %1, off sc0 sc1"
                     : "=v"(v[jj]) : "v"(p));
      }
      asm volatile("s_waitcnt vmcnt(0)" ::: "memory");
#pragma unroll
      for (int jj = 0; jj < 16; ++jj) {
        asm volatile("" : "+v"(v[jj]));
        *(f16x8*)&hstage[jj * 1024 + (w * 64 + lane) * 8] = v[jj];
      }
    }
    __syncthreads();  // B2: hstage ready
    f32x4 acc = {0.f, 0.f, 0.f, 0.f};
    if (t > 0) {
      f32x4 a0 = {0,0,0,0}, a1 = {0,0,0,0}, a2 = {0,0,0,0}, a3 = {0,0,0,0};
#pragma unroll
      for (int kc = 0; kc < 32; kc += 4) {
        f16x8 h0 = *(const f16x8*)&hstage[lr * 1024 + ((((kc + 0) * 4 + (lk >> 3)) ^ (lr & 7)) * 8)];
        f16x8 h1 = *(const f16x8*)&hstage[lr * 1024 + ((((kc + 1) * 4 + (lk >> 3)) ^ (lr & 7)) * 8)];
        f16x8 h2 = *(const f16x8*)&hstage[lr * 1024 + ((((kc + 2) * 4 + (lk >> 3)) ^ (lr & 7)) * 8)];
        f16x8 h3 = *(const f16x8*)&hstage[lr * 1024 + ((((kc + 3) * 4 + (lk >> 3)) ^ (lr & 7)) * 8)];
        a0 = __builtin_amdgcn_mfma_f32_16x16x32_f16(h0, bf[kc + 0], a0, 0, 0, 0);
        a1 = __builtin_amdgcn_mfma_f32_16x16x32_f16(h1, bf[kc + 1], a1, 0, 0, 0);
        a2 = __builtin_amdgcn_mfma_f32_16x16x32_f16(h2, bf[kc + 2], a2, 0, 0, 0);
        a3 = __builtin_amdgcn_mfma_f32_16x16x32_f16(h3, bf[kc + 3], a3, 0, 0, 0);
      }
      acc = (a0 + a1) + (a2 + a3);
    }
    if (w < 2) {
#pragma unroll
      for (int r = 0; r < 4; ++r) ldsRZ[w][rrow + r][lr] = acc[r] + bhw;
    }
    __syncthreads();  // B3: r/z published
    if (w == 2) {
      float hmv[4];
#pragma unroll
      for (int r = 0; r < 4; ++r) {
        const float hr = ldsRZ[0][rrow + r][lr];
        const float hz = ldsRZ[1][rrow + r][lr];
        const float hn = acc[r] + bhw;
        const float rg = sigm(xr[r] + bi0 + hr);
        const float zg = sigm(xz[r] + bi1 + hz);
        const float ng = tanh_fast(xn[r] + bi2 + rg * hn);
        const float hnew = (1.f - zg) * ng + zg * hprev[r];
        const float mm = mt[r];
        const float hm = mm * hnew + (1.f - mm) * hprev[r];
        hprev[r] = hm;
        hmv[r] = hm;
      }
      // h stores LLC-direct -> ack -> flag (shortest possible release path)
      f16* hb = hbuf + (size_t)((t + 1) & 1) * (64 * 1024);
#pragma unroll
      for (int r = 0; r < 4; ++r) {
        f16* p = hb + (size_t)(m0 + rrow + r) * 1024 + j;
        unsigned short u = __builtin_bit_cast(unsigned short, (f16)hmv[r]);
        asm volatile("global_store_short %0, %1, off sc0 sc1"
                     :: "v"(p), "v"(u) : "memory");
      }
      asm volatile("s_waitcnt vmcnt(0)" ::: "memory");
      if (lane == 0)
        __hip_atomic_store(&myflags[c], t + 1, __ATOMIC_RELAXED, __HIP_MEMORY_SCOPE_AGENT);
      // off-critical-path: outputs + next-step xW prefetch (overlap readers)
#pragma unroll
      for (int r = 0; r < 4; ++r) {
        const int b = m0 + rrow + r;
        __builtin_nontemporal_store(hmv[r], &out[(size_t)(b * 512 + t) * 1024 + j]);
        if (t == NT - 1)
          __builtin_nontemporal_store(hmv[r], &out[(size_t)64 * 512 * 1024 + (size_t)b * 1024 + j]);
      }
      const int tn = (t + 1 < NT) ? t + 1 : NT - 1;
#pragma unroll
      for (int r = 0; r < 4; ++r) {
        const int b = m0 + rrow + r;
        xr[r] = (float)__builtin_nontemporal_load(&xw[(size_t)((tn * 3 + 0) * 64 + b) * 1024 + j]);
        xz[r] = (float)__builtin_nontemporal_load(&xw[(size_t)((tn * 3 + 1) * 64 + b) * 1024 + j]);
        xn[r] = (float)__builtin_nontemporal_load(&xw[(size_t)((tn * 3 + 2) * 64 + b) * 1024 + j]);
        mt[r] = smix[rrow + r][tn];
      }
    }
  }
}

// ---------------------------------------------------------------------------
extern "C" void kernel_launch(void* const* d_in, const int* in_sizes, int n_in,
                              void* d_out, int out_size, void* d_ws, size_t ws_size,
                              hipStream_t stream) {
  const float* x    = (const float*)d_in[0];
  const float* mixp = (const float*)d_in[1];
  const float* Wih  = (const float*)d_in[2];
  const float* Whh  = (const float*)d_in[3];
  const float* bih  = (const float*)d_in[4];
  const float* bhh  = (const float*)d_in[5];
  float* out = (float*)d_out;

  const size_t XW_BYTES = (size_t)512 * 3 * 64 * 1024 * sizeof(f16);  // 201326592
  f16* xw    = (f16*)d_ws;
  f16* hbuf  = (f16*)((char*)d_ws + XW_BYTES);
  int* flags = (int*)((char*)d_ws + XW_BYTES + (size_t)2 * 64 * 1024 * sizeof(f16));

  hipMemsetAsync(flags, 0, 4 * 64 * sizeof(int), stream);

  dim3 gg(24, 256);
  gemm_xw<<<gg, 256, 0, stream>>>(x, Wih, xw);

  dim3 gr(64, 4);
  recur<<<gr, 192, 0, stream>>>(xw, mixp, Whh, bih, bhh, out, hbuf, flags);
}